// Round 8
// baseline (453.504 us; speedup 1.0000x reference)
//
#include <hip/hip_runtime.h>
#include <cmath>

typedef __bf16 bf16x8 __attribute__((ext_vector_type(8)));
typedef __bf16 bf16x4 __attribute__((ext_vector_type(4)));
typedef float  f32x4  __attribute__((ext_vector_type(4)));

template <int N> struct IC { static constexpr int v = N; };

#define ATILE 32768   // one K-tile of A: 256 rows * 128 B (bf16, [ks][row][64])
#define WBUF  16384   // one W window in LDS: 32 rows * 512 B bf16 (swizzled)

#define SBAR()  __builtin_amdgcn_s_barrier()
#define SCHED() __builtin_amdgcn_sched_barrier(0)

__device__ __forceinline__ bf16x8 cvt8(f32x4 a, f32x4 b) {
    bf16x8 r;
    r[0] = (__bf16)a[0]; r[1] = (__bf16)a[1]; r[2] = (__bf16)a[2]; r[3] = (__bf16)a[3];
    r[4] = (__bf16)b[0]; r[5] = (__bf16)b[1]; r[6] = (__bf16)b[2]; r[7] = (__bf16)b[3];
    return r;
}
__device__ __forceinline__ bf16x4 cvt4(f32x4 a) {
    bf16x4 r;
    r[0] = (__bf16)a[0]; r[1] = (__bf16)a[1]; r[2] = (__bf16)a[2]; r[3] = (__bf16)a[3];
    return r;
}

// A0 = concat(cat,x,hid) bf16, K-tiled [ks][row][64 cols].
__global__ __launch_bounds__(256)
void prep_xc(const float* __restrict__ cat, const float* __restrict__ x,
             const float* __restrict__ hid, unsigned char* __restrict__ A0)
{
    int id  = blockIdx.x * 256 + threadIdx.x;
    int row = id >> 9, col = (id & 511) * 8;
    const float* src = (col < 512)  ? cat + (size_t)row * 512 + col
                     : (col < 2048) ? x   + (size_t)row * 1536 + (col - 512)
                                    : hid + (size_t)row * 2048 + (col - 2048);
    f32x4 a = *(const f32x4*)src, b = *(const f32x4*)(src + 4);
    *(bf16x8*)(A0 + (size_t)(col >> 6) * ATILE + row * 128 + (col & 63) * 2) = cvt8(a, b);
}

// Full-K narrow-N GEMM: BN=32, K=4096, 512 thr = 8 waves x 32 M-rows.
// W is consumed in 16 windows of 256 K; each W row is read strictly
// sequentially (1 KB chunk per window) -> per-block DRAM pattern = 32
// sequential streams over a contiguous 512 KB panel. Counted vmcnt(4)
// (never 0 until the tail) keeps the next window always in flight.
// MODE 0: gates (512 blocks x 8 cells x 4 gates), fused LSTM epilogue.
// MODE 1: vocab (1000 blocks x 32 cols), bias epilogue.
template <int MODE>
__global__ __launch_bounds__(512, 4)
void gemm_fk(const unsigned char* __restrict__ At,
             const float* __restrict__ W0, const float* __restrict__ W1,
             const float* __restrict__ W2, const float* __restrict__ W3,
             const float* __restrict__ B0, const float* __restrict__ B1,
             const float* __restrict__ B2, const float* __restrict__ B3,
             const float* __restrict__ cell,
             float* __restrict__ out0, float* __restrict__ out1,
             unsigned char* __restrict__ A1out)
{
    __shared__ __align__(16) unsigned char lds[2 * WBUF];   // 32 KB

    const int tid  = threadIdx.x;
    const int lane = tid & 63;
    const int wid  = tid >> 6;       // wave: M-rows [wid*32, wid*32+32)
    const int l15  = lane & 15;
    const int l4   = lane >> 4;

    // ---- W staging assignment: 512 thr = 32 rows x 16 lanes ----
    const int rb = tid >> 4, li = tid & 15;
    const float* rowp;
    if constexpr (MODE == 0) {
        const int gate = rb & 3;
        const int cl   = blockIdx.x * 8 + (rb >> 2);
        const float* Wg = (gate == 0) ? W0 : (gate == 1) ? W1
                        : (gate == 2) ? W2 : W3;
        rowp = Wg + (size_t)cl * 4096 + li * 4;
    } else {
        rowp = W0 + (size_t)(blockIdx.x * 32 + rb) * 4096 + li * 4;
    }
    const int sw = (rb & 7) << 4;

    f32x4 wa[4], wb[4];              // two named prefetch sets (rule #20)
    auto issueW = [&](int w, f32x4 (&set)[4]) {
        const float* p = rowp + w * 256;
        #pragma unroll
        for (int i = 0; i < 4; ++i)
            set[i] = __builtin_nontemporal_load((const f32x4*)(p + i * 64));
    };
    auto stageW = [&](int w, f32x4 (&set)[4]) {
        unsigned char* b = lds + (w & 1) * WBUF + rb * 512;
        #pragma unroll
        for (int i = 0; i < 4; ++i)
            *(bf16x4*)(b + ((li * 8 + i * 128) ^ sw)) = cvt4(set[i]);
    };

    f32x4 acc[2][2] = {};            // [m][nf]

    auto compute_win = [&](int w) {
        const unsigned char* buf = lds + (w & 1) * WBUF;
        #pragma unroll
        for (int h = 0; h < 2; ++h) {
            bf16x8 af[4][2];
            #pragma unroll
            for (int s4 = 0; s4 < 4; ++s4) {
                const int s = h * 4 + s4;
                const int ks = w * 4 + (s >> 1), kk = s & 1;
                #pragma unroll
                for (int m = 0; m < 2; ++m) {
                    const int row = wid * 32 + m * 16 + l15;
                    af[s4][m] = *(const bf16x8*)(At + (size_t)ks * ATILE +
                                                 row * 128 + kk * 64 + l4 * 16);
                }
            }
            #pragma unroll
            for (int s4 = 0; s4 < 4; ++s4) {
                const int s = h * 4 + s4;
                bf16x8 bw[2];
                #pragma unroll
                for (int nf = 0; nf < 2; ++nf) {
                    const int r = nf * 16 + l15;
                    bw[nf] = *(const bf16x8*)(buf + r * 512 +
                               ((s * 64 + l4 * 16) ^ ((r & 7) << 4)));
                }
                #pragma unroll
                for (int m = 0; m < 2; ++m)
                    #pragma unroll
                    for (int nf = 0; nf < 2; ++nf)
                        acc[m][nf] = __builtin_amdgcn_mfma_f32_16x16x32_bf16(
                            af[s4][m], bw[nf], acc[m][nf], 0, 0, 0);
            }
        }
    };

    auto head = [&](int w, f32x4 (&set)[4], auto vmc) {
        if constexpr (decltype(vmc)::v == 4)
            asm volatile("s_waitcnt vmcnt(4)" ::: "memory");
        else
            asm volatile("s_waitcnt vmcnt(0)" ::: "memory");
        SCHED();
        stageW(w, set);                       // cvt + 4x ds_write_b64
        if (w + 2 < 16) issueW(w + 2, set);   // refill the freed set
        SCHED();
        asm volatile("s_waitcnt lgkmcnt(0)" ::: "memory");
        SBAR(); SCHED();
    };

    issueW(0, wa);
    issueW(1, wb);
    for (int wp = 0; wp < 7; ++wp) {
        const int w = wp * 2;
        head(w,     wa, IC<4>{}); compute_win(w);
        head(w + 1, wb, IC<4>{}); compute_win(w + 1);
    }
    head(14, wa, IC<4>{}); compute_win(14);
    head(15, wb, IC<0>{}); compute_win(15);

    if constexpr (MODE == 0) {
        // ---- fused LSTM epilogue ----
        SBAR();                                // all LDS reads of window 15 done
        float* zl = (float*)lds;               // 256 x 32 fp32 = 32 KB
        #pragma unroll
        for (int m = 0; m < 2; ++m)
            #pragma unroll
            for (int nf = 0; nf < 2; ++nf)
                #pragma unroll
                for (int j = 0; j < 4; ++j)
                    zl[(wid * 32 + m * 16 + l4 * 4 + j) * 32 + nf * 16 + l15] =
                        acc[m][nf][j];
        asm volatile("s_waitcnt lgkmcnt(0)" ::: "memory");
        SBAR();

        const int row = tid >> 1, cb = (tid & 1) * 4;
        const int c0  = blockIdx.x * 8;
        f32x4 cv = *(const f32x4*)(cell + (size_t)row * 4096 + c0 + cb);
        f32x4 rc, rh; bf16x4 hb;
        #pragma unroll
        for (int cl = 0; cl < 4; ++cl) {
            const int c = cb + cl;
            const float fz = zl[row * 32 + c * 4 + 0] + B0[c0 + c];
            const float iz = zl[row * 32 + c * 4 + 1] + B1[c0 + c];
            const float gz = zl[row * 32 + c * 4 + 2] + B2[c0 + c];
            const float oz = zl[row * 32 + c * 4 + 3] + B3[c0 + c];
            const float f = 1.0f / (1.0f + __expf(-fz));
            const float i = 1.0f / (1.0f + __expf(-iz));
            const float g = tanhf(gz);
            const float o = 1.0f / (1.0f + __expf(-oz));
            const float cn = f * cv[cl] + i * g;
            const float hn = o * tanhf(cn);
            rc[cl] = cn; rh[cl] = hn; hb[cl] = (__bf16)hn;
        }
        *(f32x4*)(out0 + (size_t)row * 4096 + c0 + cb) = rc;
        *(f32x4*)(out1 + (size_t)row * 4096 + c0 + cb) = rh;
        *(bf16x4*)(A1out + (size_t)(c0 >> 6) * ATILE + row * 128 +
                   ((c0 & 63) + cb) * 2) = hb;
    } else {
        const int n0 = blockIdx.x * 32;
        #pragma unroll
        for (int nf = 0; nf < 2; ++nf) {
            const int col = n0 + nf * 16 + l15;
            const float bias = B0[col];
            #pragma unroll
            for (int m = 0; m < 2; ++m) {
                const int r = wid * 32 + m * 16 + l4 * 4;
                f32x4 v = acc[m][nf];
                #pragma unroll
                for (int j = 0; j < 4; ++j)
                    out0[(size_t)(r + j) * 32000 + col] = v[j] + bias;
            }
        }
    }
}

__global__ __launch_bounds__(256)
void logsoftmax_inplace(float* __restrict__ out)
{
    float* row    = out + (size_t)blockIdx.x * 32000;
    const int tid = threadIdx.x;
    __shared__ float redm[4], reds[4];

    float m = -1e30f, s = 0.0f;
    for (int i = tid; i < 8000; i += 256) {
        f32x4 v = *(const f32x4*)(row + i * 4);
        float t = fmaxf(fmaxf(v[0], v[1]), fmaxf(v[2], v[3]));
        float nm = fmaxf(m, t);
        s = s * __expf(m - nm) + __expf(v[0] - nm) + __expf(v[1] - nm)
                               + __expf(v[2] - nm) + __expf(v[3] - nm);
        m = nm;
    }
    #pragma unroll
    for (int off = 32; off; off >>= 1) {
        float om = __shfl_xor(m, off), os = __shfl_xor(s, off);
        float nm = fmaxf(m, om);
        s = s * __expf(m - nm) + os * __expf(om - nm);
        m = nm;
    }
    if ((tid & 63) == 0) { redm[tid >> 6] = m; reds[tid >> 6] = s; }
    __syncthreads();
    {
        float M = fmaxf(fmaxf(redm[0], redm[1]), fmaxf(redm[2], redm[3]));
        float S = reds[0] * __expf(redm[0] - M) + reds[1] * __expf(redm[1] - M)
                + reds[2] * __expf(redm[2] - M) + reds[3] * __expf(redm[3] - M);
        m = M; s = S;
    }
    float lse = m + logf(s);

    for (int i = tid; i < 8000; i += 256) {
        f32x4 v = *(const f32x4*)(row + i * 4);
        v[0] -= lse; v[1] -= lse; v[2] -= lse; v[3] -= lse;
        *(f32x4*)(row + i * 4) = v;
    }
}

extern "C" void kernel_launch(void* const* d_in, const int* in_sizes, int n_in,
                              void* d_out, int out_size, void* d_ws, size_t ws_size,
                              hipStream_t stream)
{
    const float* cat  = (const float*)d_in[0];
    const float* x    = (const float*)d_in[1];
    const float* hid  = (const float*)d_in[2];
    const float* cell = (const float*)d_in[3];
    const float* Wf   = (const float*)d_in[4];
    const float* bf   = (const float*)d_in[5];
    const float* Wi   = (const float*)d_in[6];
    const float* bi   = (const float*)d_in[7];
    const float* Wc   = (const float*)d_in[8];
    const float* bc   = (const float*)d_in[9];
    const float* Wo   = (const float*)d_in[10];
    const float* bo   = (const float*)d_in[11];
    const float* Wout = (const float*)d_in[12];
    const float* bout = (const float*)d_in[13];
    float* out = (float*)d_out;

    // ws: A0 bf16 xc tiles (2MB) | A1 bf16 hidden tiles (2MB)
    unsigned char* A0 = (unsigned char*)d_ws;
    unsigned char* A1 = A0 + (size_t)64 * ATILE;

    // d_out: [logits 256x32000 | cell_new 256x4096 | hidden_new 256x4096]
    float* cnew = out + 8192000;
    float* hnew = out + 9240576;

    prep_xc<<<512, 256, 0, stream>>>(cat, x, hid, A0);
    // gates + fused LSTM: 512 blocks x (8 cells x 4 gates)
    gemm_fk<0><<<512, 512, 0, stream>>>(A0, Wf, Wi, Wc, Wo, bf, bi, bc, bo,
                                        cell, cnew, hnew, A1);
    // vocab: 1000 blocks x 32 cols
    gemm_fk<1><<<1000, 512, 0, stream>>>(A1, Wout, nullptr, nullptr, nullptr,
                                         bout, nullptr, nullptr, nullptr,
                                         nullptr, out, nullptr, nullptr);
    logsoftmax_inplace<<<256, 256, 0, stream>>>(out);
}